// Round 3
// baseline (511.720 us; speedup 1.0000x reference)
//
#include <hip/hip_runtime.h>

// NeurTWs fused position-encoder + merge-layer. One thread per row.
// R3: everything fully unrolled, ALL register arrays constant-indexed
// (no scratch demotion — R1 failure), ALL 16 feat float4 gathers issued
// upfront as one vmcnt-batched group (no per-iteration vmcnt(0)
// serialization — R2 failure). Weights are wave-uniform -> s_load/SGPR
// operands fused into v_fma_f32. Peak live VGPR ~160 -> bounds (256,3).

__global__ __launch_bounds__(256, 3) void neurtw_fused(
    const float* __restrict__ pos_table,   // [NUM_KEYS, 4]
    const float* __restrict__ node_feat,   // [NUM_NODES, 64]
    const float* __restrict__ W1,          // [4, 32]
    const float* __restrict__ b1,          // [32]
    const float* __restrict__ W2,          // [32, 32]
    const float* __restrict__ b2,          // [32]
    const float* __restrict__ Wm1,         // [96, 64]
    const float* __restrict__ bm1,         // [64]
    const float* __restrict__ Wm2,         // [64, 1]
    const float* __restrict__ bm2,         // [1]
    const int*   __restrict__ key_idx,     // [B*M]
    const int*   __restrict__ node_idx,    // [B*M]
    float*       __restrict__ out,         // [B*M]
    int rows)
{
    const int row = blockIdx.x * 256 + threadIdx.x;
    if (row >= rows) return;

    const int k  = key_idx[row];
    const int nd = node_idx[row];

    // ---- issue ALL gathers upfront: 1 pos float4 + 16 feat float4 ----
    const float4 enc = *(const float4*)(pos_table + (size_t)k * 4);
    const float4* f4ptr = (const float4*)(node_feat + (size_t)nd * 64);
    float4 f[16];
    #pragma unroll
    for (int i = 0; i < 16; ++i) f[i] = f4ptr[i];   // constant idx -> VGPRs

    const float e0 = enc.x, e1 = enc.y, e2 = enc.z, e3 = enc.w;

    // ---- GEMM1: h1 = relu(enc @ W1 + b1), [32] ----
    float h1[32];
    #pragma unroll
    for (int j = 0; j < 32; ++j) {
        float a = fmaf(e3, W1[96 + j],
                  fmaf(e2, W1[64 + j],
                  fmaf(e1, W1[32 + j],
                  fmaf(e0, W1[j], b1[j]))));
        h1[j] = fmaxf(a, 0.0f);
    }

    // ---- GEMM2: pe = h1 @ W2 + b2, [32] ----
    float pe[32];
    #pragma unroll
    for (int j = 0; j < 32; ++j) pe[j] = b2[j];
    #pragma unroll
    for (int i = 0; i < 32; ++i) {
        const float hv = h1[i];
        #pragma unroll
        for (int j = 0; j < 32; ++j)
            pe[j] = fmaf(hv, W2[i * 32 + j], pe[j]);
    }

    // ---- GEMM3: acc = concat(pe, feat) @ Wm1 + bm1, [64] ----
    float acc[64];
    #pragma unroll
    for (int c = 0; c < 64; ++c) acc[c] = bm1[c];

    // pe half first (pe dies here, freeing 32 regs before feat peak)
    #pragma unroll
    for (int j = 0; j < 32; ++j) {
        const float xv = pe[j];
        #pragma unroll
        for (int c = 0; c < 64; ++c)
            acc[c] = fmaf(xv, Wm1[j * 64 + c], acc[c]);
    }

    // feat half, fully unrolled; f[g] constant-indexed, dies as consumed
    #pragma unroll
    for (int g = 0; g < 16; ++g) {
        const float xs[4] = { f[g].x, f[g].y, f[g].z, f[g].w };
        #pragma unroll
        for (int q = 0; q < 4; ++q) {
            const float xv = xs[q];
            const int jrow = 32 + 4 * g + q;
            #pragma unroll
            for (int c = 0; c < 64; ++c)
                acc[c] = fmaf(xv, Wm1[jrow * 64 + c], acc[c]);
        }
    }

    // ---- GEMM4: z = relu(acc) @ Wm2 + bm2 ----
    float z = bm2[0];
    #pragma unroll
    for (int c = 0; c < 64; ++c)
        z = fmaf(fmaxf(acc[c], 0.0f), Wm2[c], z);

    out[row] = z;
}

extern "C" void kernel_launch(void* const* d_in, const int* in_sizes, int n_in,
                              void* d_out, int out_size, void* d_ws, size_t ws_size,
                              hipStream_t stream) {
    const float* pos_table = (const float*)d_in[0];
    const float* node_feat = (const float*)d_in[1];
    const float* W1        = (const float*)d_in[2];
    const float* b1        = (const float*)d_in[3];
    const float* W2        = (const float*)d_in[4];
    const float* b2        = (const float*)d_in[5];
    const float* Wm1       = (const float*)d_in[6];
    const float* bm1       = (const float*)d_in[7];
    const float* Wm2       = (const float*)d_in[8];
    const float* bm2       = (const float*)d_in[9];
    const int*   key_idx   = (const int*)d_in[10];
    const int*   node_idx  = (const int*)d_in[11];
    float* out = (float*)d_out;

    const int rows = in_sizes[10];            // B*M = 1,048,576
    const int grid = (rows + 255) / 256;
    neurtw_fused<<<grid, 256, 0, stream>>>(
        pos_table, node_feat, W1, b1, W2, b2, Wm1, bm1, Wm2, bm2,
        key_idx, node_idx, out, rows);
}

// Round 4
// 174.325 us; speedup vs baseline: 2.9354x; 2.9354x over previous
//
#include <hip/hip_runtime.h>

// NeurTWs fused pipeline on MFMA (f16 in, fp32 accum).
// Block = 256 threads = 4 waves; each wave owns 64 rows.
// Per block:
//   P0: stage W2^T, Wm1^T into LDS as f16 (B-fragment friendly: [n][k]).
//   P1: per-thread gather enc, GEMM1 (128 VALU FMA) -> relu -> f16 -> h_lds.
//   P2: GEMM2 via 8 MFMAs/wave (A from h_lds, B = W2^T), +b2 -> pe_lds (f16).
//   P3: GEMM3 via 48 MFMAs/wave: ktile0 A from pe_lds; ktiles 1-2 A loaded
//       DIRECTLY from global node_feat (8 contiguous fp32/lane, prefetched
//       upfront -> no LDS staging of feat, no serialized gathers).
//   P4: relu + Wm2 dot in regs, 4-step __shfl_xor reduce over n-group, store.
// Fragment layouts (verified on gfx950): A: m=lane&15, k=(lane>>4)*8+j;
// B: n=lane&15, k=(lane>>4)*8+j; C/D: col=lane&15, row=(lane>>4)*4+reg.

typedef _Float16 half8 __attribute__((ext_vector_type(8)));
typedef float floatx4 __attribute__((ext_vector_type(4)));

#define HSTR 40    // h_lds/pe_lds/w2t row stride (f16): 80B, 16B-aligned, ~2-way banks
#define WSTR 104   // wm1t row stride (f16): 208B, 16B-aligned

__global__ __launch_bounds__(256, 2) void neurtw_mfma(
    const float* __restrict__ pos_table,   // [NUM_KEYS, 4]
    const float* __restrict__ node_feat,   // [NUM_NODES, 64]
    const float* __restrict__ W1,          // [4, 32]
    const float* __restrict__ b1,          // [32]
    const float* __restrict__ W2,          // [32, 32]
    const float* __restrict__ b2,          // [32]
    const float* __restrict__ Wm1,         // [96, 64]
    const float* __restrict__ bm1,         // [64]
    const float* __restrict__ Wm2,         // [64, 1]
    const float* __restrict__ bm2,         // [1]
    const int*   __restrict__ key_idx,     // [B*M]
    const int*   __restrict__ node_idx,    // [B*M]
    float*       __restrict__ out)         // [B*M]
{
    __shared__ _Float16 h_lds[256 * HSTR];   // 20 KB
    __shared__ _Float16 pe_lds[256 * HSTR];  // 20 KB
    __shared__ _Float16 w2t[32 * HSTR];      // 2.5 KB  w2t[n][k] = W2[k][n]
    __shared__ _Float16 wm1t[64 * WSTR];     // 13 KB   wm1t[n][k] = Wm1[k][n]
    __shared__ int nd_lds[256];              // 1 KB

    const int tid = threadIdx.x;
    const int blockBase = blockIdx.x * 256;
    const int row = blockBase + tid;

    // ---------------- P0: stage transposed weights as f16 ----------------
    #pragma unroll
    for (int i = 0; i < 24; ++i) {               // Wm1: 6144 elems
        const int idx = i * 256 + tid;           // idx = k*64 + n
        const int k = idx >> 6, n = idx & 63;
        wm1t[n * WSTR + k] = (_Float16)Wm1[idx];
    }
    #pragma unroll
    for (int i = 0; i < 4; ++i) {                // W2: 1024 elems
        const int idx = i * 256 + tid;           // idx = k*32 + n
        const int k = idx >> 5, n = idx & 31;
        w2t[n * HSTR + k] = (_Float16)W2[idx];
    }

    // ---------------- P1: gather + GEMM1 (VALU fp32) ----------------
    nd_lds[tid] = node_idx[row];
    const int kk = key_idx[row];
    const float4 enc = *(const float4*)(pos_table + (size_t)kk * 4);

    {
        #pragma unroll
        for (int g = 0; g < 4; ++g) {            // 4 groups of 8 outputs
            half8 hv;
            #pragma unroll
            for (int j8 = 0; j8 < 8; ++j8) {
                const int j = g * 8 + j8;
                float a = fmaf(enc.w, W1[96 + j],
                          fmaf(enc.z, W1[64 + j],
                          fmaf(enc.y, W1[32 + j],
                          fmaf(enc.x, W1[j], b1[j]))));
                hv[j8] = (_Float16)fmaxf(a, 0.0f);
            }
            *(half8*)(&h_lds[tid * HSTR + g * 8]) = hv;
        }
    }
    __syncthreads();

    // wave coordinates
    const int lane = tid & 63;
    const int r0 = (tid >> 6) * 64;              // wave's row slice in block
    const int ln = lane & 15;                    // n / m within tile
    const int q  = lane >> 4;                    // quad

    // ---------------- P2: GEMM2 via MFMA -> pe_lds ----------------
    {
        half8 a_h[4];
        #pragma unroll
        for (int rt = 0; rt < 4; ++rt)
            a_h[rt] = *(const half8*)(&h_lds[(r0 + rt * 16 + ln) * HSTR + q * 8]);
        half8 b_w2[2];
        #pragma unroll
        for (int ct = 0; ct < 2; ++ct)
            b_w2[ct] = *(const half8*)(&w2t[(ct * 16 + ln) * HSTR + q * 8]);

        const float b2v0 = b2[ln], b2v1 = b2[16 + ln];

        #pragma unroll
        for (int rt = 0; rt < 4; ++rt) {
            #pragma unroll
            for (int ct = 0; ct < 2; ++ct) {
                floatx4 c = {0.f, 0.f, 0.f, 0.f};
                c = __builtin_amdgcn_mfma_f32_16x16x32_f16(a_h[rt], b_w2[ct], c, 0, 0, 0);
                const float bb = ct ? b2v1 : b2v0;
                #pragma unroll
                for (int r = 0; r < 4; ++r)
                    pe_lds[(r0 + rt * 16 + q * 4 + r) * HSTR + ct * 16 + ln] =
                        (_Float16)(c[r] + bb);
            }
        }
    }
    __syncthreads();

    // ---------------- P3: GEMM3 via MFMA ----------------
    floatx4 acc[4][4];
    {
        // prefetch ALL feat fragments from global (constant-indexed regs)
        float4 fr[4][2][2];
        #pragma unroll
        for (int rt = 0; rt < 4; ++rt) {
            const int rowl = r0 + rt * 16 + ln;          // A-row this lane needs
            const int ndm = nd_lds[rowl];
            const float* fb = node_feat + (size_t)ndm * 64 + q * 8;
            #pragma unroll
            for (int kt = 0; kt < 2; ++kt) {
                fr[rt][kt][0] = *(const float4*)(fb + kt * 32);
                fr[rt][kt][1] = *(const float4*)(fb + kt * 32 + 4);
            }
        }

        // init acc with bm1 (col = ct*16 + ln, same col for all 4 regs)
        #pragma unroll
        for (int ct = 0; ct < 4; ++ct) {
            const float bb = bm1[ct * 16 + ln];
            #pragma unroll
            for (int rt = 0; rt < 4; ++rt)
                acc[rt][ct] = (floatx4){bb, bb, bb, bb};
        }

        // ktile 0: A = pe from LDS
        {
            half8 a_pe[4];
            #pragma unroll
            for (int rt = 0; rt < 4; ++rt)
                a_pe[rt] = *(const half8*)(&pe_lds[(r0 + rt * 16 + ln) * HSTR + q * 8]);
            half8 b0[4];
            #pragma unroll
            for (int ct = 0; ct < 4; ++ct)
                b0[ct] = *(const half8*)(&wm1t[(ct * 16 + ln) * WSTR + q * 8]);
            #pragma unroll
            for (int rt = 0; rt < 4; ++rt)
                #pragma unroll
                for (int ct = 0; ct < 4; ++ct)
                    acc[rt][ct] = __builtin_amdgcn_mfma_f32_16x16x32_f16(
                        a_pe[rt], b0[ct], acc[rt][ct], 0, 0, 0);
        }

        // ktiles 1,2: A = feat (from prefetched regs), B from wm1t
        #pragma unroll
        for (int kt = 0; kt < 2; ++kt) {
            half8 bk[4];
            #pragma unroll
            for (int ct = 0; ct < 4; ++ct)
                bk[ct] = *(const half8*)(&wm1t[(ct * 16 + ln) * WSTR + 32 + kt * 32 + q * 8]);
            #pragma unroll
            for (int rt = 0; rt < 4; ++rt) {
                half8 ak;
                const float4 lo = fr[rt][kt][0], hi = fr[rt][kt][1];
                ak[0] = (_Float16)lo.x; ak[1] = (_Float16)lo.y;
                ak[2] = (_Float16)lo.z; ak[3] = (_Float16)lo.w;
                ak[4] = (_Float16)hi.x; ak[5] = (_Float16)hi.y;
                ak[6] = (_Float16)hi.z; ak[7] = (_Float16)hi.w;
                #pragma unroll
                for (int ct = 0; ct < 4; ++ct)
                    acc[rt][ct] = __builtin_amdgcn_mfma_f32_16x16x32_f16(
                        ak, bk[ct], acc[rt][ct], 0, 0, 0);
            }
        }
    }

    // ---------------- P4: relu + Wm2 dot + butterfly reduce + store ----------------
    {
        float wm2v[4];
        #pragma unroll
        for (int ct = 0; ct < 4; ++ct) wm2v[ct] = Wm2[ct * 16 + ln];
        const float bm2s = bm2[0];

        #pragma unroll
        for (int rt = 0; rt < 4; ++rt) {
            #pragma unroll
            for (int r = 0; r < 4; ++r) {
                float p = 0.0f;
                #pragma unroll
                for (int ct = 0; ct < 4; ++ct)
                    p = fmaf(fmaxf(acc[rt][ct][r], 0.0f), wm2v[ct], p);
                p += __shfl_xor(p, 1);
                p += __shfl_xor(p, 2);
                p += __shfl_xor(p, 4);
                p += __shfl_xor(p, 8);
                if (ln == 0)
                    out[blockBase + r0 + rt * 16 + q * 4 + r] = p + bm2s;
            }
        }
    }
}

extern "C" void kernel_launch(void* const* d_in, const int* in_sizes, int n_in,
                              void* d_out, int out_size, void* d_ws, size_t ws_size,
                              hipStream_t stream) {
    const float* pos_table = (const float*)d_in[0];
    const float* node_feat = (const float*)d_in[1];
    const float* W1        = (const float*)d_in[2];
    const float* b1        = (const float*)d_in[3];
    const float* W2        = (const float*)d_in[4];
    const float* b2        = (const float*)d_in[5];
    const float* Wm1       = (const float*)d_in[6];
    const float* bm1       = (const float*)d_in[7];
    const float* Wm2       = (const float*)d_in[8];
    const float* bm2       = (const float*)d_in[9];
    const int*   key_idx   = (const int*)d_in[10];
    const int*   node_idx  = (const int*)d_in[11];
    float* out = (float*)d_out;

    const int rows = in_sizes[10];            // B*M = 1,048,576 (multiple of 256)
    const int grid = rows / 256;
    neurtw_mfma<<<grid, 256, 0, stream>>>(
        pos_table, node_feat, W1, b1, W2, b2, Wm1, bm1, Wm2, bm2,
        key_idx, node_idx, out);
}

// Round 5
// 158.887 us; speedup vs baseline: 3.2206x; 1.0972x over previous
//
#include <hip/hip_runtime.h>

// NeurTWs fused pipeline on MFMA, R5: persistent grid-stride blocks.
// Block = 256 threads = 4 waves; each wave owns 64 rows per iteration.
// - Weights staged ONCE per block (wm1t -> LDS via conflict-free b128;
//   W2/bias fragments hoisted to registers from global).
// - One 20 KB LDS buffer reused h -> pe (slices are wave-private; 2 syncs
//   per iter protect the write->read transpose hazards).
// - node_feat pre-converted to f16 in d_ws (halves gather bytes + kills
//   inline cvt); fp32 fallback path if ws_size too small.
// Fragment layouts (gfx950, verified): A/B: idx=lane&15, k=(lane>>4)*8+j;
// C/D: col=lane&15, row=(lane>>4)*4+reg.

typedef _Float16 half8 __attribute__((ext_vector_type(8)));
typedef float floatx4 __attribute__((ext_vector_type(4)));

#define HSTR 40    // h/pe row stride in f16 (80 B = 5 x 16B chunks, odd -> conflict-free)
#define WSTR 104   // wm1t row stride in f16 (208 B = 13 chunks, odd -> conflict-free)
#define GRID 768   // 3 blocks/CU x 256 CUs

__global__ void feat_to_f16(const float* __restrict__ nf,
                            _Float16* __restrict__ o, int n8) {
    int t = blockIdx.x * 256 + threadIdx.x;
    if (t >= n8) return;
    const float4* p = (const float4*)nf + (size_t)t * 2;
    const float4 a = p[0], b = p[1];
    half8 h;
    h[0] = (_Float16)a.x; h[1] = (_Float16)a.y;
    h[2] = (_Float16)a.z; h[3] = (_Float16)a.w;
    h[4] = (_Float16)b.x; h[5] = (_Float16)b.y;
    h[6] = (_Float16)b.z; h[7] = (_Float16)b.w;
    *((half8*)o + t) = h;
}

__global__ __launch_bounds__(256, 3) void neurtw_mfma(
    const float* __restrict__ pos_table,   // [NUM_KEYS, 4]
    const float* __restrict__ node_feat,   // [NUM_NODES, 64]
    const float* __restrict__ W1,          // [4, 32]
    const float* __restrict__ b1,          // [32]
    const float* __restrict__ W2,          // [32, 32]
    const float* __restrict__ b2,          // [32]
    const float* __restrict__ Wm1,         // [96, 64]
    const float* __restrict__ bm1,         // [64]
    const float* __restrict__ Wm2,         // [64, 1]
    const float* __restrict__ bm2,         // [1]
    const int*   __restrict__ key_idx,     // [rows]
    const int*   __restrict__ node_idx,    // [rows]
    const _Float16* __restrict__ feat16,   // [NUM_NODES, 64] f16 (ws) or null
    int use_f16,
    float*       __restrict__ out,         // [rows]
    int rows)
{
    __shared__ _Float16 hpe[256 * HSTR];   // 20 KB (h, then pe; wave-private slices)
    __shared__ _Float16 wm1t[64 * WSTR];   // 13 KB  wm1t[n][k] = Wm1[k][n]

    const int tid  = threadIdx.x;
    const int lane = tid & 63;
    const int r0   = (tid >> 6) * 64;      // wave's row slice within block
    const int ln   = lane & 15;
    const int q    = lane >> 4;

    // ---------- once per block: stage Wm1^T into LDS ----------
    // 768 tasks = (n 0..63) x (k8 0..11); b128 writes, 13-chunk rows ->
    // chunk = (13n + k8) mod 8 covers all 8 bank-groups evenly.
    #pragma unroll
    for (int i = 0; i < 3; ++i) {
        const int task = i * 256 + tid;
        const int n = task & 63, k8 = task >> 6;
        half8 w;
        #pragma unroll
        for (int kk = 0; kk < 8; ++kk)
            w[kk] = (_Float16)Wm1[(k8 * 8 + kk) * 64 + n];
        *(half8*)(&wm1t[n * WSTR + k8 * 8]) = w;
    }

    // ---------- once per block: per-lane weight/bias fragments ----------
    half8 b_w2[2];
    #pragma unroll
    for (int ct = 0; ct < 2; ++ct)
        #pragma unroll
        for (int j = 0; j < 8; ++j)
            b_w2[ct][j] = (_Float16)W2[(q * 8 + j) * 32 + ct * 16 + ln];
    float b2v[2];
    b2v[0] = b2[ln]; b2v[1] = b2[16 + ln];
    float bm1v[4], wm2v[4];
    #pragma unroll
    for (int ct = 0; ct < 4; ++ct) {
        bm1v[ct] = bm1[ct * 16 + ln];
        wm2v[ct] = Wm2[ct * 16 + ln];
    }
    const float bm2s = bm2[0];

    __syncthreads();   // wm1t staged

    for (int base = blockIdx.x * 256; base < rows; base += GRID * 256) {
        const int row = base + tid;

        // ---- iteration top: issue ALL global loads first ----
        int ndr[4];
        #pragma unroll
        for (int rt = 0; rt < 4; ++rt)
            ndr[rt] = node_idx[base + r0 + rt * 16 + ln];

        half8 fA[4][2];                    // feat A-fragments (prefetched)
        if (use_f16) {
            #pragma unroll
            for (int rt = 0; rt < 4; ++rt) {
                const _Float16* fb = feat16 + (size_t)ndr[rt] * 64 + q * 8;
                fA[rt][0] = *(const half8*)(fb);
                fA[rt][1] = *(const half8*)(fb + 32);
            }
        } else {
            #pragma unroll
            for (int rt = 0; rt < 4; ++rt) {
                const float* fb = node_feat + (size_t)ndr[rt] * 64 + q * 8;
                #pragma unroll
                for (int kt = 0; kt < 2; ++kt) {
                    const float4 lo = *(const float4*)(fb + kt * 32);
                    const float4 hi = *(const float4*)(fb + kt * 32 + 4);
                    half8 h;
                    h[0] = (_Float16)lo.x; h[1] = (_Float16)lo.y;
                    h[2] = (_Float16)lo.z; h[3] = (_Float16)lo.w;
                    h[4] = (_Float16)hi.x; h[5] = (_Float16)hi.y;
                    h[6] = (_Float16)hi.z; h[7] = (_Float16)hi.w;
                    fA[rt][kt] = h;
                }
            }
        }

        const int kk = key_idx[row];
        const float4 enc = *(const float4*)(pos_table + (size_t)kk * 4);

        // ---- GEMM1 (VALU fp32, uniform weights via s_load) -> h ----
        #pragma unroll
        for (int g = 0; g < 4; ++g) {
            half8 hv;
            #pragma unroll
            for (int j8 = 0; j8 < 8; ++j8) {
                const int j = g * 8 + j8;
                float a = fmaf(enc.w, W1[96 + j],
                          fmaf(enc.z, W1[64 + j],
                          fmaf(enc.y, W1[32 + j],
                          fmaf(enc.x, W1[j], b1[j]))));
                hv[j8] = (_Float16)fmaxf(a, 0.0f);
            }
            *(half8*)(&hpe[tid * HSTR + g * 8]) = hv;
        }
        __syncthreads();   // h visible (also orders vs prev-iter readers)

        // ---- GEMM2: 8 MFMA -> pe (C-layout regs) ----
        half8 a_h[4];
        #pragma unroll
        for (int rt = 0; rt < 4; ++rt)
            a_h[rt] = *(const half8*)(&hpe[(r0 + rt * 16 + ln) * HSTR + q * 8]);

        floatx4 pc[4][2];
        #pragma unroll
        for (int rt = 0; rt < 4; ++rt)
            #pragma unroll
            for (int ct = 0; ct < 2; ++ct) {
                floatx4 c = {0.f, 0.f, 0.f, 0.f};
                pc[rt][ct] = __builtin_amdgcn_mfma_f32_16x16x32_f16(
                    a_h[rt], b_w2[ct], c, 0, 0, 0);
            }

        // write pe into the SAME buffer (h already consumed; own slice only)
        #pragma unroll
        for (int rt = 0; rt < 4; ++rt)
            #pragma unroll
            for (int ct = 0; ct < 2; ++ct)
                #pragma unroll
                for (int r = 0; r < 4; ++r)
                    hpe[(r0 + rt * 16 + q * 4 + r) * HSTR + ct * 16 + ln] =
                        (_Float16)(pc[rt][ct][r] + b2v[ct]);
        __syncthreads();   // pe visible

        // ---- GEMM3: 48 MFMA ----
        floatx4 acc[4][4];
        #pragma unroll
        for (int ct = 0; ct < 4; ++ct) {
            const float bb = bm1v[ct];
            #pragma unroll
            for (int rt = 0; rt < 4; ++rt)
                acc[rt][ct] = (floatx4){bb, bb, bb, bb};
        }

        {   // ktile 0: A = pe from LDS
            half8 a_pe[4];
            #pragma unroll
            for (int rt = 0; rt < 4; ++rt)
                a_pe[rt] = *(const half8*)(&hpe[(r0 + rt * 16 + ln) * HSTR + q * 8]);
            half8 b0[4];
            #pragma unroll
            for (int ct = 0; ct < 4; ++ct)
                b0[ct] = *(const half8*)(&wm1t[(ct * 16 + ln) * WSTR + q * 8]);
            #pragma unroll
            for (int rt = 0; rt < 4; ++rt)
                #pragma unroll
                for (int ct = 0; ct < 4; ++ct)
                    acc[rt][ct] = __builtin_amdgcn_mfma_f32_16x16x32_f16(
                        a_pe[rt], b0[ct], acc[rt][ct], 0, 0, 0);
        }

        #pragma unroll
        for (int kt = 0; kt < 2; ++kt) {   // ktiles 1,2: A = feat (prefetched)
            half8 bk[4];
            #pragma unroll
            for (int ct = 0; ct < 4; ++ct)
                bk[ct] = *(const half8*)(&wm1t[(ct * 16 + ln) * WSTR + 32 + kt * 32 + q * 8]);
            #pragma unroll
            for (int rt = 0; rt < 4; ++rt)
                #pragma unroll
                for (int ct = 0; ct < 4; ++ct)
                    acc[rt][ct] = __builtin_amdgcn_mfma_f32_16x16x32_f16(
                        fA[rt][kt], bk[ct], acc[rt][ct], 0, 0, 0);
        }

        // ---- GEMM4: relu + Wm2 dot + 4-step butterfly + store ----
        #pragma unroll
        for (int rt = 0; rt < 4; ++rt) {
            #pragma unroll
            for (int r = 0; r < 4; ++r) {
                float p = 0.0f;
                #pragma unroll
                for (int ct = 0; ct < 4; ++ct)
                    p = fmaf(fmaxf(acc[rt][ct][r], 0.0f), wm2v[ct], p);
                p += __shfl_xor(p, 1);
                p += __shfl_xor(p, 2);
                p += __shfl_xor(p, 4);
                p += __shfl_xor(p, 8);
                if (ln == 0)
                    out[base + r0 + rt * 16 + q * 4 + r] = p + bm2s;
            }
        }
    }
}

extern "C" void kernel_launch(void* const* d_in, const int* in_sizes, int n_in,
                              void* d_out, int out_size, void* d_ws, size_t ws_size,
                              hipStream_t stream) {
    const float* pos_table = (const float*)d_in[0];
    const float* node_feat = (const float*)d_in[1];
    const float* W1        = (const float*)d_in[2];
    const float* b1        = (const float*)d_in[3];
    const float* W2        = (const float*)d_in[4];
    const float* b2        = (const float*)d_in[5];
    const float* Wm1       = (const float*)d_in[6];
    const float* bm1       = (const float*)d_in[7];
    const float* Wm2       = (const float*)d_in[8];
    const float* bm2       = (const float*)d_in[9];
    const int*   key_idx   = (const int*)d_in[10];
    const int*   node_idx  = (const int*)d_in[11];
    float* out = (float*)d_out;

    const int rows = in_sizes[10];                 // B*M = 1,048,576
    const int nfeat = in_sizes[1];                 // NUM_NODES*64
    const size_t need = (size_t)nfeat * sizeof(_Float16);
    const int use_f16 = (ws_size >= need) ? 1 : 0;

    if (use_f16) {
        const int n8 = nfeat / 8;
        feat_to_f16<<<(n8 + 255) / 256, 256, 0, stream>>>(
            node_feat, (_Float16*)d_ws, n8);
    }

    neurtw_mfma<<<GRID, 256, 0, stream>>>(
        pos_table, node_feat, W1, b1, W2, b2, Wm1, bm1, Wm2, bm2,
        key_idx, node_idx, (const _Float16*)d_ws, use_f16, out, rows);
}